// Round 3
// baseline (1596.118 us; speedup 1.0000x reference)
//
#include <hip/hip_runtime.h>
#include <math.h>

// Problem constants (from reference): N_EDGES=500000, N_RELS=256, D=256.
#define D 256
#define R 256
#define DIMC 64  // dims per y-block

__device__ __forceinline__ float sigmoidf(float x) {
    return 1.0f / (1.0f + expf(-x));
}

// ---- kernel 1: zero workspace (harness poisons ws with 0xAA every call) ----
__global__ void zero_ws(float* ws, int n) {
    int i = blockIdx.x * blockDim.x + threadIdx.x;
    if (i < n) ws[i] = 0.0f;
}

// ---- kernel 2: relation histogram (counts as float, integer-exact) ----
__global__ __launch_bounds__(256) void hist_kernel(const int* __restrict__ rel,
                                                   int E,
                                                   float* __restrict__ counts) {
    __shared__ int h[R];
    h[threadIdx.x] = 0;
    __syncthreads();
    for (int e = blockIdx.x * blockDim.x + threadIdx.x; e < E;
         e += gridDim.x * blockDim.x)
        atomicAdd(&h[rel[e]], 1);
    __syncthreads();
    atomicAdd(&counts[threadIdx.x], (float)h[threadIdx.x]);
}

// ---- kernel 3: gather + LDS-privatized segment sum, LANE-PER-EDGE ----
// Each lane owns one edge: loads that edge's 64-dim slice as 4 chunks of
// 4x float4. Every global_load_dwordx4 has 64 independent random rows in
// flight (vs 1 row/instr in the old wave-per-edge readlane scheme) -> MLP
// limited by the memory system, not the schedule. No readlane chains.
// Accumulator is transposed+swizzled: acc[d][r ^ (d&31)] so per-lane
// scattered atomics (random rel) spread across all 32 banks, the flush
// read is conflict-free, and the global flush stays coalesced. Exactly
// 64KB -> 2 blocks/CU, 32 waves/CU.
__global__ __launch_bounds__(1024, 8) void scatter_kernel(
    const int* __restrict__ src_nid, const int* __restrict__ dst_nid,
    const int* __restrict__ rel, const float* __restrict__ emb,
    float* __restrict__ src_sum, float* __restrict__ dst_sum, int E, int epb) {
    __shared__ float acc[R * DIMC];  // 64 KB, layout [d][r ^ (d&31)]
    const int tid = threadIdx.x;
    for (int i = tid; i < R * DIMC; i += 1024) acc[i] = 0.0f;
    __syncthreads();

    const int* nids = blockIdx.z ? dst_nid : src_nid;
    float* gsum     = blockIdx.z ? dst_sum : src_sum;
    const int dimbase = blockIdx.y * DIMC;
    const int lane = tid & 63;
    const int wave = tid >> 6;  // 0..15
    const int start = blockIdx.x * epb;
    const int end   = (start + epb < E) ? (start + epb) : E;

    for (int base = start + wave * 64; base < end; base += 1024) {
        const int e = base + lane;
        const bool valid = e < end;
        int mynid = 0, myrel = 0;
        if (valid) {
            mynid = nids[e];
            myrel = rel[e];
        }
        const float4* row =
            (const float4*)(emb + (size_t)mynid * D + dimbase);
#pragma unroll
        for (int c = 0; c < 4; c++) {
            float4 v[4];
#pragma unroll
            for (int k = 0; k < 4; k++) v[k] = row[c * 4 + k];
            if (valid) {
#pragma unroll
                for (int k = 0; k < 4; k++) {
                    const int d0 = c * 16 + k * 4;
                    atomicAdd(&acc[(d0 + 0) * R + (myrel ^ ((d0 + 0) & 31))], v[k].x);
                    atomicAdd(&acc[(d0 + 1) * R + (myrel ^ ((d0 + 1) & 31))], v[k].y);
                    atomicAdd(&acc[(d0 + 2) * R + (myrel ^ ((d0 + 2) & 31))], v[k].z);
                    atomicAdd(&acc[(d0 + 3) * R + (myrel ^ ((d0 + 3) & 31))], v[k].w);
                }
            }
        }
    }
    __syncthreads();
    // flush: d = i&63 varies across lanes -> global addrs consecutive
    // (coalesced 256B) and LDS banks (r ^ (d&31)) all distinct.
    for (int i = tid; i < R * DIMC; i += 1024) {
        const int d = i & (DIMC - 1);
        const int r = i >> 6;
        atomicAdd(&gsum[r * D + dimbase + d], acc[d * R + (r ^ (d & 31))]);
    }
}

// ---- kernel 4: means + GRU cell, one block per relation, 512 threads ----
// src side = waves 0-3, dst side = waves 4-7 (wave-uniform side select so
// LDS reads stay broadcast). Halves the per-block critical path vs the old
// 256-thread both-sides-per-thread version (which ran 1 wave/SIMD).
__global__ __launch_bounds__(512) void gru_kernel(
    const float* __restrict__ src_sum, const float* __restrict__ dst_sum,
    const float* __restrict__ counts, const float* __restrict__ dyn,
    const float* __restrict__ W_ih, const float* __restrict__ W_hh,
    const float* __restrict__ b_ih, const float* __restrict__ b_hh,
    float* __restrict__ out) {
    __shared__ float x2[2][D], h2[2][D];
    const int r = blockIdx.x, t = threadIdx.x;
    const int s = t >> 8;       // 0 = src, 1 = dst (wave-uniform)
    const int tt = t & 255;
    const float inv = 1.0f / fmaxf(counts[r], 1.0f);
    float h_old;
    if (s == 0) {
        x2[0][tt] = src_sum[r * D + tt] * inv;
        h_old = dyn[(r * D + tt) * 2 + 0];
        h2[0][tt] = h_old;
    } else {
        x2[1][tt] = dst_sum[r * D + tt] * inv;
        h_old = dyn[(r * D + tt) * 2 + 1];
        h2[1][tt] = h_old;
    }
    __syncthreads();
    const float* xs = x2[s];
    const float* hs = h2[s];

    float gi[3], gh[3];
#pragma unroll
    for (int g = 0; g < 3; g++) {
        const int row = g * D + tt;
        const float4* wi = (const float4*)(W_ih + (size_t)row * D);
        const float4* wh = (const float4*)(W_hh + (size_t)row * D);
        float ai = 0.f, ah = 0.f;
        for (int k = 0; k < D / 4; k++) {
            float4 a = wi[k];
            float4 b = wh[k];
            int k4 = k * 4;
            ai += a.x * xs[k4] + a.y * xs[k4 + 1] + a.z * xs[k4 + 2] + a.w * xs[k4 + 3];
            ah += b.x * hs[k4] + b.y * hs[k4 + 1] + b.z * hs[k4 + 2] + b.w * hs[k4 + 3];
        }
        gi[g] = ai + b_ih[row];
        gh[g] = ah + b_hh[row];
    }
    const float rr = sigmoidf(gi[0] + gh[0]);
    const float zz = sigmoidf(gi[1] + gh[1]);
    const float nn = tanhf(gi[2] + rr * gh[2]);
    const float nh = (1.0f - zz) * nn + zz * h_old;

    // Output shape (R,1,D,2) flat, fp32.
    out[(r * D + tt) * 2 + s] = nh;
}

extern "C" void kernel_launch(void* const* d_in, const int* in_sizes, int n_in,
                              void* d_out, int out_size, void* d_ws, size_t ws_size,
                              hipStream_t stream) {
    const int* src_nid = (const int*)d_in[0];
    const int* dst_nid = (const int*)d_in[1];
    const int* rel     = (const int*)d_in[2];
    const float* emb   = (const float*)d_in[3];
    const float* dyn   = (const float*)d_in[4];
    const float* W_ih  = (const float*)d_in[5];
    const float* W_hh  = (const float*)d_in[6];
    const float* b_ih  = (const float*)d_in[7];
    const float* b_hh  = (const float*)d_in[8];
    float* out = (float*)d_out;
    const int E = in_sizes[0];

    float* ws      = (float*)d_ws;
    float* src_sum = ws;               // R*D
    float* dst_sum = ws + R * D;       // R*D
    float* counts  = ws + 2 * R * D;   // R
    const int nzero = 2 * R * D + R;

    zero_ws<<<(nzero + 255) / 256, 256, 0, stream>>>(ws, nzero);
    hist_kernel<<<256, 256, 0, stream>>>(rel, E, counts);

    // 64 x 4 x 2 = 512 blocks of 1024 threads -> 2 blocks/CU, 32 waves/CU
    const int chunks = 64;
    const int epb = (E + chunks - 1) / chunks;  // edges per block
    scatter_kernel<<<dim3(chunks, 4, 2), 1024, 0, stream>>>(
        src_nid, dst_nid, rel, emb, src_sum, dst_sum, E, epb);

    gru_kernel<<<R, 512, 0, stream>>>(src_sum, dst_sum, counts, dyn, W_ih, W_hh,
                                      b_ih, b_hh, out);
}